// Round 7
// baseline (293.649 us; speedup 1.0000x reference)
//
#include <hip/hip_runtime.h>
#include <stdint.h>

#define IN_DIM 1024
#define OUT_DIM 1024
#define NROWS 8192
#define KD 3072            // B ws layout: k = (p-1)*1024 + i (k=0 folded into bias)

#define BM 256
#define BN 128
#define NIC 16             // 16 i-chunks of 64; chunk = i-chunk x {p=1,2,3}

typedef __bf16 bf16x8 __attribute__((ext_vector_type(8)));
typedef float f32x4 __attribute__((ext_vector_type(4)));
typedef unsigned short us8 __attribute__((ext_vector_type(8)));
typedef unsigned int u32;

#define AS1 __attribute__((address_space(1)))
#define AS3 __attribute__((address_space(3)))

__device__ __forceinline__ unsigned short f2bf(float f) {
    u32 u = __builtin_bit_cast(u32, f);
    u32 r = (u + 0x7fffu + ((u >> 16) & 1u)) >> 16;   // RNE, finite inputs
    return (unsigned short)r;
}

__device__ __forceinline__ bf16x8 ld8(const unsigned short* p) {
    return __builtin_bit_cast(bf16x8, *reinterpret_cast<const us8*>(p));
}

// ---- prep: coeffs fp32 -> bf16 B[OUT_DIM][KD] (k-major), c0 folded into bias2 ----
__global__ __launch_bounds__(256) void prep_coeffs(const float* __restrict__ c,
                                                   const float* __restrict__ bias,
                                                   unsigned short* __restrict__ B,
                                                   float* __restrict__ bias2) {
    const int o = blockIdx.x;
    const float4* row = reinterpret_cast<const float4*>(c + (size_t)o * (IN_DIM * 4));
    unsigned short* Bo = B + (size_t)o * KD;
    float s = 0.f;
    for (int i = threadIdx.x; i < IN_DIM; i += 256) {
        float4 v = row[i];            // {c0, c1, c2, c3} for (o, i)
        s += v.x;
        Bo[i]        = f2bf(v.y);
        Bo[1024 + i] = f2bf(v.z);
        Bo[2048 + i] = f2bf(v.w);
    }
#pragma unroll
    for (int off = 32; off; off >>= 1) s += __shfl_down(s, off);
    __shared__ float red[4];
    if ((threadIdx.x & 63) == 0) red[threadIdx.x >> 6] = s;
    __syncthreads();
    if (threadIdx.x == 0) bias2[o] = bias[o] + red[0] + red[1] + red[2] + red[3];
}

// ---- fused GEMM: C[n][o] = sum_{p,i} x[n][i]^p * Bws[o][(p-1)*1024+i] + bias2 ----
// A generated in-register from x; only B LDS-staged. 512 thr / 8 waves
// (4M x 2N, wave 64x64). Chunk = 64 i-cols x 3 powers (96 MFMA/wave).
// Cross-chunk REGISTER prefetch of x (ping-pong xqA/xqB) + B glds issued
// together right after the barrier: compute consumes only registers and
// already-landed LDS, so the top-of-chunk vmcnt(0) waits on loads issued a
// full chunk (~1900 cyc) earlier. T2 swizzle pair (conflicts=0 verified), T5.
__global__ __launch_bounds__(512, 2) void taylor_gemm(
    const float* __restrict__ x,            // fp32 [NROWS][IN_DIM]
    const unsigned short* __restrict__ B,   // bf16 [OUT_DIM][KD]
    const float* __restrict__ bias2,
    float* __restrict__ C) {
    __shared__ alignas(16) unsigned short sB[2][3][BN * 64];  // 2 x 3 x 16 KiB

    const int tid = threadIdx.x;
    const int lane = tid & 63;
    const int wid = tid >> 6;       // 0..7
    const int wr = wid >> 1;        // 0..3  (M quarter: 64 rows)
    const int wc = wid & 1;         // 0..1  (N half: 64 cols)
    const int gx = blockIdx.x, gy = blockIdx.y;

    // ---- B staging: 6 glds/wave/chunk (3 powers x 2 units), T2 pair ----
    const char* Bb = (const char*)B;
    const int cs = ((lane & 7) ^ (lane >> 3)) * 8;   // swizzled source col (ushort)
    size_t bSrc[2];
    int bDst[2];
#pragma unroll
    for (int u = 0; u < 2; ++u) {
        int row = gy * BN + u * 64 + wid * 8 + (lane >> 3);
        bSrc[u] = ((size_t)row * KD + cs) * 2;
        bDst[u] = (u * 64 + wid * 8) * 64;
    }

    auto stage_all = [&](int d, int ic) {
        size_t koff = (size_t)(ic * 64) * 2;
#pragma unroll
        for (int pp = 0; pp < 3; ++pp)
#pragma unroll
            for (int u = 0; u < 2; ++u)
                __builtin_amdgcn_global_load_lds(
                    (const AS1 void*)(Bb + bSrc[u] + (size_t)pp * 2048 + koff),
                    (AS3 void*)(&sB[d][pp][bDst[u]]), 16, 0, 0);
    };

    // swizzled B-frag read base (ushort idx), per ks
    int bSw[2];
#pragma unroll
    for (int ks = 0; ks < 2; ++ks)
        bSw[ks] = (wc * 64 + (lane & 15)) * 64 + (((ks * 4 + (lane >> 4)) ^ (lane & 7)) * 8);

    // x fragment base pointers: (m): row gx*BM + wr*64 + m*16 + (lane&15),
    // cols (lane>>4)*8 + ic*64 + ks*32
    const float* xb[4];
#pragma unroll
    for (int m = 0; m < 4; ++m)
        xb[m] = x + (size_t)(gx * BM + wr * 64 + m * 16 + (lane & 15)) * IN_DIM
                  + ((lane >> 4) * 8);

    float4 xqA[4][2][2], xqB[4][2][2];
    f32x4 acc[4][4] = {};

    auto load_x = [&](float4 (&xq)[4][2][2], int ic) {
#pragma unroll
        for (int m = 0; m < 4; ++m)
#pragma unroll
            for (int ks = 0; ks < 2; ++ks) {
                const float* p = xb[m] + ic * 64 + ks * 32;
                xq[m][ks][0] = *reinterpret_cast<const float4*>(p);
                xq[m][ks][1] = *reinterpret_cast<const float4*>(p + 4);
            }
    };

    auto compute = [&](int d, float4 (&xq)[4][2][2]) {
#pragma unroll
        for (int pp = 0; pp < 3; ++pp) {
            bf16x8 fb[4][2];
#pragma unroll
            for (int n = 0; n < 4; ++n)
#pragma unroll
                for (int ks = 0; ks < 2; ++ks)
                    fb[n][ks] = ld8(&sB[d][pp][bSw[ks] + n * 16 * 64]);
#pragma unroll
            for (int m = 0; m < 4; ++m) {
                bf16x8 af[2];
#pragma unroll
                for (int ks = 0; ks < 2; ++ks) {
                    float v[8] = {xq[m][ks][0].x, xq[m][ks][0].y,
                                  xq[m][ks][0].z, xq[m][ks][0].w,
                                  xq[m][ks][1].x, xq[m][ks][1].y,
                                  xq[m][ks][1].z, xq[m][ks][1].w};
#pragma unroll
                    for (int j = 0; j < 8; ++j) {
                        float w = v[j];
                        if (pp >= 1) w *= v[j];
                        if (pp == 2) w *= v[j];
                        af[ks][j] = (__bf16)w;
                    }
                }
                __builtin_amdgcn_s_setprio(1);
#pragma unroll
                for (int n = 0; n < 4; ++n)
#pragma unroll
                    for (int ks = 0; ks < 2; ++ks)
                        acc[m][n] = __builtin_amdgcn_mfma_f32_16x16x32_bf16(
                            af[ks], fb[n][ks], acc[m][n], 0, 0, 0);
                __builtin_amdgcn_s_setprio(0);
            }
        }
    };

    // prologue: issue x(0) + B(0)
    load_x(xqA, 0);
    stage_all(0, 0);

    // per chunk: wait(everything issued one chunk ago) -> barrier ->
    // issue x(ic+1)+B(ic+1) -> compute(ic) from regs + landed LDS.
#define TAYLOR_CHUNK(ic, CUR, NXT)                                            \
    {                                                                         \
        asm volatile("s_waitcnt vmcnt(0)" ::: "memory");                      \
        __builtin_amdgcn_s_barrier();                                         \
        __builtin_amdgcn_sched_barrier(0);                                    \
        if ((ic) + 1 < NIC) {                                                 \
            load_x(NXT, (ic) + 1);                                            \
            stage_all(((ic) + 1) & 1, (ic) + 1);                              \
        }                                                                     \
        __builtin_amdgcn_sched_barrier(0);                                    \
        compute((ic) & 1, CUR);                                               \
    }

    for (int ic = 0; ic < NIC; ic += 2) {
        TAYLOR_CHUNK(ic,     xqA, xqB);
        TAYLOR_CHUNK(ic + 1, xqB, xqA);
    }
#undef TAYLOR_CHUNK

    // epilogue: C/D layout col = lane&15, row = (lane>>4)*4 + r
    const int colBase = gy * BN + wc * 64 + (lane & 15);
    const int rowBase = gx * BM + wr * 64 + (lane >> 4) * 4;
#pragma unroll
    for (int n = 0; n < 4; ++n) {
        int col = colBase + n * 16;
        float bv = bias2[col];
#pragma unroll
        for (int m = 0; m < 4; ++m) {
            int row = rowBase + m * 16;
#pragma unroll
            for (int r = 0; r < 4; ++r)
                C[(size_t)(row + r) * OUT_DIM + col] = acc[m][n][r] + bv;
        }
    }
}

// ---- fallback (ws too small): fp32 LDS-staged, correct but slow ----
__global__ void taylor_naive(const float* __restrict__ x, const float* __restrict__ coeffs,
                             const float* __restrict__ bias, float* __restrict__ out) {
    int n = blockIdx.x;
    __shared__ float P[IN_DIM * 4];
    for (int i = threadIdx.x; i < IN_DIM; i += blockDim.x) {
        float xv = x[(size_t)n * IN_DIM + i];
        P[i * 4 + 0] = 1.f;
        P[i * 4 + 1] = xv;
        P[i * 4 + 2] = xv * xv;
        P[i * 4 + 3] = xv * xv * xv;
    }
    __syncthreads();
    for (int o = threadIdx.x; o < OUT_DIM; o += blockDim.x) {
        float s = bias[o];
        const float* c = coeffs + (size_t)o * (IN_DIM * 4);
        for (int i = 0; i < IN_DIM; ++i) {
            float4 cv = *reinterpret_cast<const float4*>(c + i * 4);
            s += cv.x * P[i * 4 + 0] + cv.y * P[i * 4 + 1] +
                 cv.z * P[i * 4 + 2] + cv.w * P[i * 4 + 3];
        }
        out[(size_t)n * OUT_DIM + o] = s;
    }
}

extern "C" void kernel_launch(void* const* d_in, const int* in_sizes, int n_in,
                              void* d_out, int out_size, void* d_ws, size_t ws_size,
                              hipStream_t stream) {
    const float* x = (const float*)d_in[0];
    const float* coeffs = (const float*)d_in[1];
    const float* bias = (const float*)d_in[2];
    float* out = (float*)d_out;

    const size_t needB = (size_t)OUT_DIM * KD * 2;   // 6 MiB
    const size_t needBias = OUT_DIM * sizeof(float); // 4 KiB

    if (ws_size >= needB + needBias) {
        unsigned short* B = (unsigned short*)d_ws;
        float* bias2 = (float*)((char*)d_ws + needB);
        prep_coeffs<<<OUT_DIM, 256, 0, stream>>>(coeffs, bias, B, bias2);
        dim3 grid(NROWS / BM, OUT_DIM / BN);   // (32, 8) = 256 blocks, 1/CU
        taylor_gemm<<<grid, 512, 0, stream>>>(x, B, bias2, out);
    } else {
        taylor_naive<<<NROWS, 256, 0, stream>>>(x, coeffs, bias, out);
    }
}

// Round 8
// 102.374 us; speedup vs baseline: 2.8684x; 2.8684x over previous
//
#include <hip/hip_runtime.h>
#include <stdint.h>

#define IN_DIM 1024
#define OUT_DIM 1024
#define NROWS 8192
#define KD 3072            // B ws layout: k = (p-1)*1024 + i (k=0 folded into bias)

#define BM 256
#define BN 128
#define NIC 32             // 32 i-chunks of 32 cols; chunk = i-chunk x {p=1,2,3}

typedef __bf16 bf16x8 __attribute__((ext_vector_type(8)));
typedef float f32x4 __attribute__((ext_vector_type(4)));
typedef unsigned short us8 __attribute__((ext_vector_type(8)));
typedef unsigned int u32;

#define AS1 __attribute__((address_space(1)))
#define AS3 __attribute__((address_space(3)))

__device__ __forceinline__ unsigned short f2bf(float f) {
    u32 u = __builtin_bit_cast(u32, f);
    u32 r = (u + 0x7fffu + ((u >> 16) & 1u)) >> 16;   // RNE, finite inputs
    return (unsigned short)r;
}

__device__ __forceinline__ bf16x8 ld8(const unsigned short* p) {
    return __builtin_bit_cast(bf16x8, *reinterpret_cast<const us8*>(p));
}

// ---- prep: coeffs fp32 -> bf16 B[OUT_DIM][KD] (k-major), c0 folded into bias2 ----
__global__ __launch_bounds__(256) void prep_coeffs(const float* __restrict__ c,
                                                   const float* __restrict__ bias,
                                                   unsigned short* __restrict__ B,
                                                   float* __restrict__ bias2) {
    const int o = blockIdx.x;
    const float4* row = reinterpret_cast<const float4*>(c + (size_t)o * (IN_DIM * 4));
    unsigned short* Bo = B + (size_t)o * KD;
    float s = 0.f;
    for (int i = threadIdx.x; i < IN_DIM; i += 256) {
        float4 v = row[i];            // {c0, c1, c2, c3} for (o, i)
        s += v.x;
        Bo[i]        = f2bf(v.y);
        Bo[1024 + i] = f2bf(v.z);
        Bo[2048 + i] = f2bf(v.w);
    }
#pragma unroll
    for (int off = 32; off; off >>= 1) s += __shfl_down(s, off);
    __shared__ float red[4];
    if ((threadIdx.x & 63) == 0) red[threadIdx.x >> 6] = s;
    __syncthreads();
    if (threadIdx.x == 0) bias2[o] = bias[o] + red[0] + red[1] + red[2] + red[3];
}

// ---- fused GEMM: C[n][o] = sum_{p,i} x[n][i]^p * Bws[o][(p-1)*1024+i] + bias2 ----
// A generated in-register from x; only B LDS-staged (48 KiB). 512 thr /
// 8 waves (4M x 2N, wave 64x64). Chunk = 32 i-cols x 3 powers = one K=32
// MFMA step per power (48 MFMA/wave/chunk). Cross-chunk register prefetch
// of x (ping-pong, 32 fp32/set) + B glds issued together after the barrier;
// top-of-chunk vmcnt(0) waits on loads issued a full chunk (~1860 cyc) ago.
// launch_bounds(512,1): LDS forces 1 block/CU anyway — do NOT cap VGPRs
// (the (512,2) cap at 128 regs caused the round-7 spill disaster).
__global__ __launch_bounds__(512, 1) void taylor_gemm(
    const float* __restrict__ x,            // fp32 [NROWS][IN_DIM]
    const unsigned short* __restrict__ B,   // bf16 [OUT_DIM][KD]
    const float* __restrict__ bias2,
    float* __restrict__ C) {
    __shared__ alignas(16) unsigned short sB[2][3][BN * 32];  // 2 x 3 x 8 KiB

    const int tid = threadIdx.x;
    const int lane = tid & 63;
    const int wid = tid >> 6;       // 0..7
    const int wr = wid >> 1;        // 0..3  (M quarter: 64 rows)
    const int wc = wid & 1;         // 0..1  (N half: 64 cols)
    const int gx = blockIdx.x, gy = blockIdx.y;

    // ---- B staging: 3 glds/wave/chunk (one 16-row slab per pp plane) ----
    // Row tile [128][32] ushort (64 B rows, 4x16B slots). Swizzle involution:
    // LDS slot u of row r holds global slot u^(r&3); reads use s^(r&3).
    const char* Bb = (const char*)B;
    {};
    const int srow = wid * 16 + (lane >> 2);             // row within 128-panel
    const int sslot = (lane & 3) ^ ((lane >> 2) & 3);    // pre-swizzled global slot
    const size_t bSrc = ((size_t)(gy * BN + srow) * KD + sslot * 8) * 2;
    const int bDst = wid * 512;                          // 16 rows x 32 ushort

    auto stage_all = [&](int d, int ic) {
        size_t koff = (size_t)ic * 64;                   // 32 cols x 2 B
#pragma unroll
        for (int pp = 0; pp < 3; ++pp)
            __builtin_amdgcn_global_load_lds(
                (const AS1 void*)(Bb + bSrc + (size_t)pp * 2048 + koff),
                (AS3 void*)(&sB[d][pp][bDst]), 16, 0, 0);
    };

    // swizzled B-frag read base (ushort idx): row r = wc*64+n*16+(lane&15),
    // slot s = lane>>4 -> addr = r*32 + ((s^(lane&3))*8)   [r&3 == lane&3]
    const int bSw = (wc * 64 + (lane & 15)) * 32 + (((lane >> 4) ^ (lane & 3)) * 8);

    // x fragment base: (m): row gx*BM + wr*64 + m*16 + (lane&15),
    // cols ic*32 + (lane>>4)*8
    const float* xb[4];
#pragma unroll
    for (int m = 0; m < 4; ++m)
        xb[m] = x + (size_t)(gx * BM + wr * 64 + m * 16 + (lane & 15)) * IN_DIM
                  + ((lane >> 4) * 8);

    float4 xqA[4][2], xqB[4][2];
    f32x4 acc[4][4] = {};

    auto load_x = [&](float4 (&xq)[4][2], int ic) {
#pragma unroll
        for (int m = 0; m < 4; ++m) {
            const float* p = xb[m] + ic * 32;
            xq[m][0] = *reinterpret_cast<const float4*>(p);
            xq[m][1] = *reinterpret_cast<const float4*>(p + 4);
        }
    };

    auto compute = [&](int d, float4 (&xq)[4][2]) {
#pragma unroll
        for (int pp = 0; pp < 3; ++pp) {
            bf16x8 fb[4];
#pragma unroll
            for (int n = 0; n < 4; ++n)
                fb[n] = ld8(&sB[d][pp][bSw + n * 16 * 32]);
#pragma unroll
            for (int m = 0; m < 4; ++m) {
                float v[8] = {xq[m][0].x, xq[m][0].y, xq[m][0].z, xq[m][0].w,
                              xq[m][1].x, xq[m][1].y, xq[m][1].z, xq[m][1].w};
                bf16x8 af;
#pragma unroll
                for (int j = 0; j < 8; ++j) {
                    float w = v[j];
                    if (pp >= 1) w *= v[j];
                    if (pp == 2) w *= v[j];
                    af[j] = (__bf16)w;
                }
                __builtin_amdgcn_s_setprio(1);
#pragma unroll
                for (int n = 0; n < 4; ++n)
                    acc[m][n] = __builtin_amdgcn_mfma_f32_16x16x32_bf16(
                        af, fb[n], acc[m][n], 0, 0, 0);
                __builtin_amdgcn_s_setprio(0);
            }
        }
    };

    // prologue: issue x(0) + B(0)
    load_x(xqA, 0);
    stage_all(0, 0);

    // per chunk: wait(loads issued one chunk ago) -> barrier ->
    // issue x(ic+1)+B(ic+1) -> compute(ic) from regs + landed LDS.
#define TAYLOR_CHUNK(ic, CUR, NXT)                                            \
    {                                                                         \
        asm volatile("s_waitcnt vmcnt(0)" ::: "memory");                      \
        __builtin_amdgcn_s_barrier();                                         \
        __builtin_amdgcn_sched_barrier(0);                                    \
        if ((ic) + 1 < NIC) {                                                 \
            load_x(NXT, (ic) + 1);                                            \
            stage_all(((ic) + 1) & 1, (ic) + 1);                              \
        }                                                                     \
        __builtin_amdgcn_sched_barrier(0);                                    \
        compute((ic) & 1, CUR);                                               \
    }

    for (int ic = 0; ic < NIC; ic += 2) {
        TAYLOR_CHUNK(ic,     xqA, xqB);
        TAYLOR_CHUNK(ic + 1, xqB, xqA);
    }
#undef TAYLOR_CHUNK

    // epilogue: C/D layout col = lane&15, row = (lane>>4)*4 + r
    const int colBase = gy * BN + wc * 64 + (lane & 15);
    const int rowBase = gx * BM + wr * 64 + (lane >> 4) * 4;
#pragma unroll
    for (int n = 0; n < 4; ++n) {
        int col = colBase + n * 16;
        float bv = bias2[col];
#pragma unroll
        for (int m = 0; m < 4; ++m) {
            int row = rowBase + m * 16;
#pragma unroll
            for (int r = 0; r < 4; ++r)
                C[(size_t)(row + r) * OUT_DIM + col] = acc[m][n][r] + bv;
        }
    }
}

// ---- fallback (ws too small): fp32 LDS-staged, correct but slow ----
__global__ void taylor_naive(const float* __restrict__ x, const float* __restrict__ coeffs,
                             const float* __restrict__ bias, float* __restrict__ out) {
    int n = blockIdx.x;
    __shared__ float P[IN_DIM * 4];
    for (int i = threadIdx.x; i < IN_DIM; i += blockDim.x) {
        float xv = x[(size_t)n * IN_DIM + i];
        P[i * 4 + 0] = 1.f;
        P[i * 4 + 1] = xv;
        P[i * 4 + 2] = xv * xv;
        P[i * 4 + 3] = xv * xv * xv;
    }
    __syncthreads();
    for (int o = threadIdx.x; o < OUT_DIM; o += blockDim.x) {
        float s = bias[o];
        const float* c = coeffs + (size_t)o * (IN_DIM * 4);
        for (int i = 0; i < IN_DIM; ++i) {
            float4 cv = *reinterpret_cast<const float4*>(c + i * 4);
            s += cv.x * P[i * 4 + 0] + cv.y * P[i * 4 + 1] +
                 cv.z * P[i * 4 + 2] + cv.w * P[i * 4 + 3];
        }
        out[(size_t)n * OUT_DIM + o] = s;
    }
}

extern "C" void kernel_launch(void* const* d_in, const int* in_sizes, int n_in,
                              void* d_out, int out_size, void* d_ws, size_t ws_size,
                              hipStream_t stream) {
    const float* x = (const float*)d_in[0];
    const float* coeffs = (const float*)d_in[1];
    const float* bias = (const float*)d_in[2];
    float* out = (float*)d_out;

    const size_t needB = (size_t)OUT_DIM * KD * 2;   // 6 MiB
    const size_t needBias = OUT_DIM * sizeof(float); // 4 KiB

    if (ws_size >= needB + needBias) {
        unsigned short* B = (unsigned short*)d_ws;
        float* bias2 = (float*)((char*)d_ws + needB);
        prep_coeffs<<<OUT_DIM, 256, 0, stream>>>(coeffs, bias, B, bias2);
        dim3 grid(NROWS / BM, OUT_DIM / BN);   // (32, 8) = 256 blocks, 1/CU
        taylor_gemm<<<grid, 512, 0, stream>>>(x, B, bias2, out);
    } else {
        taylor_naive<<<NROWS, 256, 0, stream>>>(x, coeffs, bias, out);
    }
}